// Round 7
// baseline (549.390 us; speedup 1.0000x reference)
//
#include <hip/hip_runtime.h>
#include <hip/hip_bf16.h>
#include <stdint.h>

#define E_ 8
#define B_ 16384
#define N_ 64
#define H_ 512
#define A_ 8
#define D_ 64

typedef __hip_bfloat16 bf16;
typedef __attribute__((ext_vector_type(8))) short s8v;     // 8 x bf16 (4 VGPRs)
typedef __attribute__((ext_vector_type(4))) float f4v;     // MFMA accum

__device__ __forceinline__ float bf2f(bf16 v) { return __bfloat162float(v); }
__device__ __forceinline__ bf16 f2bf(float v) { return __float2bfloat16(v); }
__device__ __forceinline__ short f2bfs(float v) {
    bf16 b = f2bf(v); short s; __builtin_memcpy(&s, &b, 2); return s;
}
__device__ __forceinline__ float bfs2f(short s) {
    bf16 b; __builtin_memcpy(&b, &s, 2); return bf2f(b);
}

__device__ __forceinline__ void async_load16(const void* g, void* l) {
    __builtin_amdgcn_global_load_lds(
        (const __attribute__((address_space(1))) void*)g,
        (__attribute__((address_space(3))) void*)l, 16, 0, 0);
}

// Swizzled LDS short-offset for a row-major [R][64]-short tile:
// slot (row, g) holds global K-group (g ^ (row&7)).  krow is a multiple of 8.
__device__ __forceinline__ int swz_off(int row, int krow) {
    return row * 64 + (((krow >> 3) ^ (row & 7)) << 3);
}

// XCD-aware block mapping: blocks sharing an A-panel (all nBn bn's of one bm)
// get linear ids differing by 8 -> same XCD (id%8), temporally adjacent.
template <int CB>
__device__ __forceinline__ void xcd_map(int x, int nBm, int& bm, int& bn) {
    if ((nBm & 7) == 0) {
        int j = x & 7, s = x >> 3;
        bn = s & ((1 << CB) - 1);
        bm = ((s >> CB) << 3) | j;
    } else {
        bm = x >> CB;
        bn = x & ((1 << CB) - 1);
    }
}

// ---------------------------------------------------------------------------
// BatchNorm statistics + fused f32->bf16 states conversion.
// ---------------------------------------------------------------------------
__global__ __launch_bounds__(256) void bnPart(const float* __restrict__ states,
                                              float* __restrict__ part,
                                              bf16* __restrict__ sbf) {
    int blk = blockIdx.x;
    int e = blk >> 6, sl = blk & 63;
    int tid = threadIdx.x, n = tid & 63, rg = tid >> 6;
    const long rowBase = (long)e * B_ + (long)sl * 256;
    const float* base = states + rowBase * 64;
    float s1 = 0.f, s2 = 0.f;
    for (int i = 0; i < 64; ++i) {
        float v = base[(rg + i * 4) * 64 + n];
        s1 += v; s2 += v * v;
        sbf[(rowBase + rg + i * 4) * 64 + n] = f2bf(v);
    }
    __shared__ float sh[2][4][64];
    sh[0][rg][n] = s1; sh[1][rg][n] = s2;
    __syncthreads();
    if (tid < 64) {
        float t1 = sh[0][0][n] + sh[0][1][n] + sh[0][2][n] + sh[0][3][n];
        float t2 = sh[1][0][n] + sh[1][1][n] + sh[1][2][n] + sh[1][3][n];
        part[((long)blk * 64 + n) * 2 + 0] = t1;
        part[((long)blk * 64 + n) * 2 + 1] = t2;
    }
}

__global__ void bnFin(const float* __restrict__ part, float* __restrict__ mu_rstd) {
    int idx = blockIdx.x * blockDim.x + threadIdx.x;  // e*64+n
    if (idx >= E_ * 64) return;
    int e = idx >> 6, n = idx & 63;
    float s1 = 0.f, s2 = 0.f;
    for (int sl = 0; sl < 64; ++sl) {
        s1 += part[(((long)e * 64 + sl) * 64 + n) * 2 + 0];
        s2 += part[(((long)e * 64 + sl) * 64 + n) * 2 + 1];
    }
    float mu = s1 / (float)B_;
    float var = s2 / (float)B_ - mu * mu;
    mu_rstd[idx * 2 + 0] = mu;
    mu_rstd[idx * 2 + 1] = rsqrtf(var + 1e-5f);
}

// Fold BN into encoder weight
__global__ void foldEnc(const float* __restrict__ W_enc, const float* __restrict__ b_enc,
                        const float* __restrict__ mu_rstd,
                        bf16* __restrict__ WencfT, float* __restrict__ bencf) {
    int idx = blockIdx.x * 256 + threadIdx.x;  // E*H = 4096
    int e = idx >> 9, h = idx & 511;
    float acc = b_enc[e * 512 + h];
    for (int n = 0; n < 64; ++n) {
        float mu = mu_rstd[(e * 64 + n) * 2 + 0];
        float rs = mu_rstd[(e * 64 + n) * 2 + 1];
        float w = W_enc[((long)e * 64 + n) * 512 + h];
        WencfT[((long)e * 512 + h) * 64 + n] = f2bf(w * rs);
        acc -= mu * rs * w;
    }
    bencf[e * 512 + h] = acc;
}

// ---------------------------------------------------------------------------
// All weight packing + pre_actions f32->bf16, fused into one dispatch.
// ---------------------------------------------------------------------------
__global__ __launch_bounds__(256) void packAll(
    const float* __restrict__ W_pre, const float* __restrict__ W_actor,
    const float* __restrict__ Wsel, const float* __restrict__ Wk,
    const float* __restrict__ Wv, const float* __restrict__ wm,
    const float* __restrict__ wl, const float* __restrict__ pre_actions,
    bf16* __restrict__ WpreT, bf16* __restrict__ WactorT, bf16* __restrict__ WselT,
    bf16* __restrict__ WkvaT, bf16* __restrict__ WmlT, bf16* __restrict__ pa_bf) {
    int bx = blockIdx.x, tid = threadIdx.x;
    if (bx < 2048) {  // WpreT / WactorT: out[n*512+k] = in[k*512+n]
        const float* in = (bx < 1024) ? W_pre : W_actor;
        bf16* out = (bx < 1024) ? WpreT : WactorT;
        int idx = (bx & 1023) * 256 + tid;
        int n = idx >> 9, k = idx & 511;
        out[idx] = f2bf(in[k * 512 + n]);
    } else if (bx < 3072) {  // WselT: [(a*64+dd)*512+h] = Wsel[a][h][dd]
        int idx = (bx - 2048) * 256 + tid;
        int n = idx >> 9, h = idx & 511;
        int a = n >> 6, dd = n & 63;
        WselT[idx] = f2bf(Wsel[((long)a * 512 + h) * 64 + dd]);
    } else if (bx < 5120) {  // WkvaT: row a*128+j -> (j<64?Wk:Wv)[a][:,j&63]
        int idx = (bx - 3072) * 256 + tid;
        int n = idx >> 9, h = idx & 511;
        int a = n >> 7, j = n & 127;
        const float* src = (j < 64) ? Wk : Wv;
        WkvaT[idx] = f2bf(src[((long)a * 512 + h) * 64 + (j & 63)]);
    } else if (bx < 5376) {  // WmlT [128][512]
        int idx = (bx - 5120) * 256 + tid;
        int n = idx >> 9, k = idx & 511;
        float v = (n < 64) ? wm[k * 64 + n] : wl[k * 64 + (n - 64)];
        WmlT[idx] = f2bf(v);
    } else {  // pa_bf: float4 cvt, 8192 blocks cover B*512/4 exactly
        int i = (bx - 5376) * 256 + tid;
        float4 v = ((const float4*)pre_actions)[i];
        bf16 o[4] = {f2bf(v.x), f2bf(v.y), f2bf(v.z), f2bf(v.w)};
        __builtin_memcpy(pa_bf + (long)i * 4, o, 8);
    }
}

// ---------------------------------------------------------------------------
// Generic MFMA GEMM, XOR-swizzled LDS, XCD-aware block mapping.
// C[M][Nn] = act(A[M][K] * BT[Nn][K]^T + bias)
// OUTF: 0 bf16 out; 1 f32 out; 2 final mean/logstd split; 4 encs [b][e][512]
// ---------------------------------------------------------------------------
template <int ACT, int OUTF, bool HAS_BIAS, int CB>
__global__ __launch_bounds__(256) void gemm_bt(
    const bf16* __restrict__ Ag, const bf16* __restrict__ Bg,
    const float* __restrict__ bias, const float* __restrict__ bias2,
    void* __restrict__ out, void* __restrict__ out2,
    int M, int Nn, int K, long sA, long sB, long sBias, long sO) {
    const int tid = threadIdx.x, lane = tid & 63, wid = tid >> 6;
    const int wm = wid >> 1, wn = wid & 1;
    int bm, bn;
    xcd_map<CB>(blockIdx.x, gridDim.x >> CB, bm, bn);
    const int bz = blockIdx.z;
    const bf16* Aptr = Ag + (long)bz * sA + (long)bm * 128 * K;
    const bf16* Bptr = Bg + (long)bz * sB + (long)bn * 128 * K;

    __shared__ __align__(16) short sAl[128 * 64];
    __shared__ __align__(16) short sBl[128 * 64];

    const int srow = lane >> 3;
    const int scol = (((lane & 7) ^ srow) << 3);

    f4v acc[4][4];
#pragma unroll
    for (int i = 0; i < 4; ++i)
#pragma unroll
        for (int j = 0; j < 4; ++j) acc[i][j] = f4v{0.f, 0.f, 0.f, 0.f};

    for (int k0 = 0; k0 < K; k0 += 64) {
#pragma unroll
        for (int i = 0; i < 4; ++i) {
            int r = (wid * 4 + i) * 8 + srow;
            async_load16(Aptr + (long)r * K + k0 + scol, (char*)sAl + (wid * 4 + i) * 1024);
            async_load16(Bptr + (long)r * K + k0 + scol, (char*)sBl + (wid * 4 + i) * 1024);
        }
        __syncthreads();
#pragma unroll
        for (int kk = 0; kk < 64; kk += 32) {
            int krow = kk + (lane >> 4) * 8;
            s8v af[4], bfr[4];
#pragma unroll
            for (int mi = 0; mi < 4; ++mi)
                af[mi] = *(const s8v*)(sAl + swz_off(wm * 64 + mi * 16 + (lane & 15), krow));
#pragma unroll
            for (int ni = 0; ni < 4; ++ni)
                bfr[ni] = *(const s8v*)(sBl + swz_off(wn * 64 + ni * 16 + (lane & 15), krow));
#pragma unroll
            for (int mi = 0; mi < 4; ++mi)
#pragma unroll
                for (int ni = 0; ni < 4; ++ni)
                    acc[mi][ni] = __builtin_amdgcn_mfma_f32_16x16x32_bf16(
                        af[mi], bfr[ni], acc[mi][ni], 0, 0, 0);
        }
        __syncthreads();
    }

    long m0 = (long)bm * 128 + wm * 64;
    long n0 = (long)bn * 128 + wn * 64;
#pragma unroll
    for (int mi = 0; mi < 4; ++mi)
#pragma unroll
        for (int ni = 0; ni < 4; ++ni)
#pragma unroll
            for (int r = 0; r < 4; ++r) {
                long gm = m0 + mi * 16 + (lane >> 4) * 4 + r;
                long gn = n0 + ni * 16 + (lane & 15);
                float v = acc[mi][ni][r];
                if constexpr (HAS_BIAS) v += bias[sBias * bz + gn];
                if constexpr (ACT == 1) v = (v >= 0.f) ? v : 0.01f * v;
                if constexpr (ACT == 2) v = fmaxf(v, 0.f);
                if constexpr (OUTF == 0) {
                    ((bf16*)out)[(long)bz * sO + gm * Nn + gn] = f2bf(v);
                } else if constexpr (OUTF == 1) {
                    ((float*)out)[(long)bz * sO + gm * Nn + gn] = v;
                } else if constexpr (OUTF == 2) {
                    if (gn < 64) {
                        ((float*)out)[gm * 64 + gn] = v + bias[gn];
                    } else {
                        float w = v + bias2[gn - 64];
                        w = fminf(fmaxf(w, -20.f), 2.f);
                        ((float*)out2)[gm * 64 + (gn - 64)] = w;
                    }
                } else {  // OUTF == 4: encs reordered [b][E][512], bz = e
                    ((bf16*)out)[(gm * E_ + bz) * 512 + gn] = f2bf(v);
                }
            }
}

// ---------------------------------------------------------------------------
// Fused keys/vals GEMM + softmax-attention (XCD-swizzled).
// A = encs [Bc*E][512] bf16 (row = b*8+e). B = WkvaT [1024][512].
// Block (bm, a): 128 rows (16 b x 8 e) x 128 cols (keys|vals of head a).
//
// This round: LDS-REUSE.  R6 showed the kernel is LDS-read-throughput-bound
// (acc[2][4] = 21.3 FLOP per LDS byte; 6.29M ds_read_b128 = 123 us of LDS
// pipe).  Revert to 64x64 wave tiles (acc[4][4], 32 FLOP/B, reads 123->82us
// floor) while KEEPING R6's single-barrier + full A/B double-buffer +
// issue-early staging.  256 threads / 4 waves; LDS 64K -> 2 blocks/CU.
// Arithmetic bit-identical.
// ---------------------------------------------------------------------------
__global__ __launch_bounds__(256, 2) void kv_attn(
    const bf16* __restrict__ Ag, const bf16* __restrict__ Bg,
    const float* __restrict__ bv, const float* __restrict__ sel,
    float* __restrict__ actor_f32, bf16* __restrict__ attn_bf, int b0) {
    const int tid = threadIdx.x, lane = tid & 63, wid = tid >> 6;
    const int wm = wid >> 1, wn = wid & 1;  // wave tile: rows wm*64, cols wn*64
    int bm, a;
    xcd_map<3>(blockIdx.x, gridDim.x >> 3, bm, a);
    const bf16* Aptr = Ag + (long)bm * 128 * 512;
    const bf16* Bptr = Bg + (long)a * 128 * 512;

    // shorts: [0,8192) A buf0  [8192,16384) A buf1  [16384,24576) B buf0
    // [24576,32768) B buf1.  Epilogue overlay: keysC [128][72] at 0 (spans
    // A dbuf, dead), vT [64][128] at 16384 (B buf0, dead).
    __shared__ __align__(16) short smem[32768];  // 64 KB
    __shared__ float lgs[128];                   // per-row logits (diag)

    const long bgBase = (long)b0 + (long)bm * 16;

    const int srow = lane >> 3;
    const int scol = (((lane & 7) ^ srow) << 3);

    auto stage = [&](int kt, int buf) {
#pragma unroll
        for (int i = 0; i < 4; ++i) {
            int r = (wid * 4 + i) * 8 + srow;
            async_load16(Aptr + (long)r * 512 + kt * 64 + scol,
                         (char*)(smem + buf * 8192) + (wid * 4 + i) * 1024);
            async_load16(Bptr + (long)r * 512 + kt * 64 + scol,
                         (char*)(smem + 16384 + buf * 8192) + (wid * 4 + i) * 1024);
        }
    };

    f4v acc[4][4];
#pragma unroll
    for (int i = 0; i < 4; ++i)
#pragma unroll
        for (int j = 0; j < 4; ++j) acc[i][j] = f4v{0.f, 0.f, 0.f, 0.f};

    stage(0, 0);
    __syncthreads();
    int cur = 0;
    for (int t = 0; t < 8; ++t) {
        if (t < 7) stage(t + 1, cur ^ 1);  // issue-early: drain covered by compute
        const short* sAc = smem + cur * 8192;
        const short* sBc = smem + 16384 + cur * 8192;
#pragma unroll
        for (int kk = 0; kk < 64; kk += 32) {
            int krow = kk + (lane >> 4) * 8;
            s8v af[4], bfr[4];
#pragma unroll
            for (int mi = 0; mi < 4; ++mi)
                af[mi] = *(const s8v*)(sAc + swz_off(wm * 64 + mi * 16 + (lane & 15), krow));
#pragma unroll
            for (int ni = 0; ni < 4; ++ni)
                bfr[ni] = *(const s8v*)(sBc + swz_off(wn * 64 + ni * 16 + (lane & 15), krow));
#pragma unroll
            for (int mi = 0; mi < 4; ++mi)
#pragma unroll
                for (int ni = 0; ni < 4; ++ni)
                    acc[mi][ni] = __builtin_amdgcn_mfma_f32_16x16x32_bf16(
                        af[mi], bfr[ni], acc[mi][ni], 0, 0, 0);
        }
        __syncthreads();  // one barrier/step: t+1 staged buffer ready, reads done
        cur ^= 1;
    }

    // ---- epilogue: keys -> keysC [128][72]; vals -> transposed swizzled vT ----
    short* keysC = smem;          // 128*72 = 9216 shorts (over A dbuf)
    short* vT    = smem + 16384;  // 64*128 shorts; vT[d*128 + (row ^ ((d&15)<<3))]
    const int quad = lane >> 4, cl = lane & 15;
#pragma unroll
    for (int mi = 0; mi < 4; ++mi)
#pragma unroll
        for (int ni = 0; ni < 4; ++ni)
#pragma unroll
            for (int r = 0; r < 4; ++r) {
                int row = wm * 64 + mi * 16 + quad * 4 + r;
                float v = acc[mi][ni][r];
                if (wn == 0) {  // keys half
                    keysC[row * 72 + ni * 16 + cl] = f2bfs(v);
                } else {        // vals half: bias + leaky, transposed store
                    int d = ni * 16 + cl;
                    v += bv[a * 64 + d];
                    v = (v >= 0.f) ? v : 0.01f * v;
                    vT[d * 128 + (row ^ ((d & 15) << 3))] = f2bfs(v);
                }
            }

    // sel B-fragments for the logits MFMA (loaded post-GEMM): lane holds
    // B[k = kk*32 + quad*8 + j][n = cl] = sel[bgBase + cl][a*64 + k] * 0.125.
    // hi+lo split keeps f32-grade precision through the bf16 MFMA.
    s8v bselH[2], bselL[2];
#pragma unroll
    for (int kk = 0; kk < 2; ++kk) {
        const float* sp = sel + (bgBase + cl) * 512 + a * 64 + kk * 32 + quad * 8;
#pragma unroll
        for (int j = 0; j < 8; ++j) {
            float s = sp[j] * 0.125f;
            short h = f2bfs(s);
            bselH[kk][j] = h;
            bselL[kk][j] = f2bfs(s - bfs2f(h));
        }
    }
    __syncthreads();

    // ---- logits via MFMA: wave wid handles rows [wid*32, wid*32+32) ----
    {
        f4v lgacc[2] = {f4v{0.f, 0.f, 0.f, 0.f}, f4v{0.f, 0.f, 0.f, 0.f}};
#pragma unroll
        for (int kk = 0; kk < 2; ++kk) {
#pragma unroll
            for (int mi = 0; mi < 2; ++mi) {
                s8v af = *(const s8v*)(keysC + (wid * 32 + mi * 16 + cl) * 72 +
                                       kk * 32 + quad * 8);
                lgacc[mi] = __builtin_amdgcn_mfma_f32_16x16x32_bf16(
                    af, bselH[kk], lgacc[mi], 0, 0, 0);
                lgacc[mi] = __builtin_amdgcn_mfma_f32_16x16x32_bf16(
                    af, bselL[kk], lgacc[mi], 0, 0, 0);
            }
        }
        // Extract diagonal: D col (lane&15) must equal b_local (= row>>3).
#pragma unroll
        for (int mi = 0; mi < 2; ++mi)
#pragma unroll
            for (int r = 0; r < 4; ++r) {
                int grow = wid * 32 + mi * 16 + quad * 4 + r;
                if (cl == (grow >> 3)) lgs[grow] = lgacc[mi][r];
            }
    }
    __syncthreads();

    // ---- attention: each wave handles 4 b's; lane = d ----
#pragma unroll
    for (int t = 0; t < 4; ++t) {
        int lb = wid * 4 + t, row0 = lb * 8;
        s8v vvv = *(const s8v*)(vT + lane * 128 + (row0 ^ ((lane & 15) << 3)));
        float lg[8], vv[8];
#pragma unroll
        for (int e = 0; e < 8; ++e) {
            vv[e] = bfs2f(vvv[e]);
            lg[e] = lgs[row0 + e];  // broadcast read
        }
        float mx = lg[0];
#pragma unroll
        for (int e = 1; e < 8; ++e) mx = fmaxf(mx, lg[e]);
        float ssum = 0.f, w[8];
#pragma unroll
        for (int e = 0; e < 8; ++e) { w[e] = __expf(lg[e] - mx); ssum += w[e]; }
        float inv = 1.f / ssum;
        float at = 0.f;
#pragma unroll
        for (int e = 0; e < 8; ++e) at += vv[e] * (w[e] * inv);
        long o = (bgBase + lb) * 512 + a * 64 + lane;
        actor_f32[o] = at;
        attn_bf[o] = f2bf(at);
    }
}

// ---------------------------------------------------------------------------
extern "C" void kernel_launch(void* const* d_in, const int* in_sizes, int n_in,
                              void* d_out, int out_size, void* d_ws, size_t ws_size,
                              hipStream_t stream) {
    (void)in_sizes; (void)n_in; (void)out_size;
    const float* states      = (const float*)d_in[0];
    const float* pre_actions = (const float*)d_in[1];
    const float* W_enc       = (const float*)d_in[2];
    const float* b_enc       = (const float*)d_in[3];
    const float* W_pre       = (const float*)d_in[4];
    const float* b_pre       = (const float*)d_in[5];
    const float* Wk          = (const float*)d_in[6];
    const float* Wsel        = (const float*)d_in[7];
    const float* Wv          = (const float*)d_in[8];
    const float* bv          = (const float*)d_in[9];
    const float* W_actor     = (const float*)d_in[10];
    const float* b_actor     = (const float*)d_in[11];
    const float* W_mean      = (const float*)d_in[12];
    const float* b_mean      = (const float*)d_in[13];
    const float* W_logstd    = (const float*)d_in[14];
    const float* b_logstd    = (const float*)d_in[15];

    char* ws = (char*)d_ws;
    size_t off = 0;
    auto alloc = [&](size_t bytes) -> void* {
        void* p = ws + off;
        off = (off + bytes + 255) & ~(size_t)255;
        return p;
    };
    float* mu_rstd = (float*)alloc((size_t)E_ * 64 * 2 * 4);
    float* bnpart  = (float*)alloc((size_t)E_ * 64 * 64 * 2 * 4);
    bf16* WencfT   = (bf16*)alloc((size_t)E_ * 512 * 64 * 2);
    float* bencf   = (float*)alloc((size_t)E_ * 512 * 4);
    bf16* WpreT    = (bf16*)alloc((size_t)512 * 512 * 2);
    bf16* WselT    = (bf16*)alloc((size_t)512 * 512 * 2);
    bf16* WkvaT    = (bf16*)alloc((size_t)1024 * 512 * 2);
    bf16* WactorT  = (bf16*)alloc((size_t)512 * 512 * 2);
    bf16* WmlT     = (bf16*)alloc((size_t)128 * 512 * 2);
    bf16* pa_bf    = (bf16*)alloc((size_t)B_ * 512 * 2);   // aliased later as p_attn
    bf16* p_pre    = (bf16*)alloc((size_t)B_ * 512 * 2);   // aliased later as p_x
    float* p_sel   = (float*)alloc((size_t)B_ * 512 * 4);
    bf16* s_bf     = (bf16*)alloc((size_t)E_ * B_ * 64 * 2);  // bf16 states (full B)
    bf16* p_attn = pa_bf;   // pre_actions bf16 dead after pre GEMM
    bf16* p_x    = p_pre;   // pre dead after sel GEMM

    // chunk over B: per-chunk bytes = Bc*(E*512*2) = Bc*8192 (encs only)
    size_t remaining = (ws_size > off) ? ws_size - off : 0;
    int Bc = B_;
    while (Bc > 128 && (size_t)Bc * 8192 + 4096 > remaining) Bc >>= 1;
    const int NC = B_ / Bc;
    bf16* c_encs = (bf16*)alloc((size_t)E_ * Bc * 512 * 2);  // [b][e][512]

    // --- prep (one fused dispatch + BN chain; bnPart also emits s_bf) ---
    packAll<<<13568, 256, 0, stream>>>(W_pre, W_actor, Wsel, Wk, Wv, W_mean, W_logstd,
                                       pre_actions, WpreT, WactorT, WselT, WkvaT, WmlT,
                                       pa_bf);
    bnPart<<<512, 256, 0, stream>>>(states, bnpart, s_bf);
    bnFin<<<2, 256, 0, stream>>>(bnpart, mu_rstd);
    foldEnc<<<16, 256, 0, stream>>>(W_enc, b_enc, mu_rstd, WencfT, bencf);

    // --- pre / sel (full B) ---
    gemm_bt<1, 0, true, 2><<<dim3((B_ / 128) << 2, 1, 1), 256, 0, stream>>>(
        pa_bf, WpreT, b_pre, nullptr, p_pre, nullptr, B_, 512, 512, 0, 0, 0, 0);
    gemm_bt<0, 1, false, 2><<<dim3((B_ / 128) << 2, 1, 1), 256, 0, stream>>>(
        p_pre, WselT, nullptr, nullptr, p_sel, nullptr, B_, 512, 512, 0, 0, 0, 0);

    // --- chunked: encoder GEMM ([b][e][512]), fused kv+attn ---
    float* actor_out = (float*)d_out + 2L * B_ * 64;
    for (int c = 0; c < NC; ++c) {
        int b0 = c * Bc;
        gemm_bt<1, 4, true, 2><<<dim3((Bc / 128) << 2, 1, E_), 256, 0, stream>>>(
            s_bf + (long)b0 * 64, WencfT, bencf, nullptr, c_encs, nullptr, Bc, 512, 64,
            (long)B_ * 64, (long)512 * 64, 512, 0);
        kv_attn<<<dim3((Bc / 16) * 8, 1, 1), 256, 0, stream>>>(
            c_encs, WkvaT, bv, p_sel, actor_out, p_attn, b0);
    }

    // --- actor + heads ---
    gemm_bt<2, 0, true, 2><<<dim3((B_ / 128) << 2, 1, 1), 256, 0, stream>>>(
        p_attn, WactorT, b_actor, nullptr, p_x, nullptr, B_, 512, 512, 0, 0, 0, 0);
    gemm_bt<0, 2, false, 0><<<dim3(B_ / 128, 1, 1), 256, 0, stream>>>(
        p_x, WmlT, b_mean, b_logstd, (float*)d_out, (float*)d_out + (long)B_ * 64,
        B_, 128, 512, 0, 0, 0, 0);
}

// Round 8
// 482.791 us; speedup vs baseline: 1.1379x; 1.1379x over previous
//
#include <hip/hip_runtime.h>
#include <hip/hip_bf16.h>
#include <stdint.h>

#define E_ 8
#define B_ 16384
#define N_ 64
#define H_ 512
#define A_ 8
#define D_ 64

typedef __hip_bfloat16 bf16;
typedef __attribute__((ext_vector_type(8))) short s8v;     // 8 x bf16 (4 VGPRs)
typedef __attribute__((ext_vector_type(4))) float f4v;     // MFMA accum

__device__ __forceinline__ float bf2f(bf16 v) { return __bfloat162float(v); }
__device__ __forceinline__ bf16 f2bf(float v) { return __float2bfloat16(v); }
__device__ __forceinline__ short f2bfs(float v) {
    bf16 b = f2bf(v); short s; __builtin_memcpy(&s, &b, 2); return s;
}
__device__ __forceinline__ float bfs2f(short s) {
    bf16 b; __builtin_memcpy(&b, &s, 2); return bf2f(b);
}

__device__ __forceinline__ void async_load16(const void* g, void* l) {
    __builtin_amdgcn_global_load_lds(
        (const __attribute__((address_space(1))) void*)g,
        (__attribute__((address_space(3))) void*)l, 16, 0, 0);
}

// Swizzled LDS short-offset for a row-major [R][64]-short tile (BK=64 kernels):
// slot (row, g) holds global K-group (g ^ (row&7)).  krow is a multiple of 8.
__device__ __forceinline__ int swz_off(int row, int krow) {
    return row * 64 + (((krow >> 3) ^ (row & 7)) << 3);
}

// Swizzled LDS short-offset for a row-major [R][32]-short tile (BK=32 kernel):
// slot (row, gs) holds global K-group gs ^ ((row>>1)&3).  To READ global
// group g of row r, use offset swz32(r, g).  Bank pattern for the fragment
// reads (16 rows x 4 groups per wave): 8-row period -> 2-way aliasing (free).
__device__ __forceinline__ int swz32(int row, int g) {
    return row * 32 + ((g ^ ((row >> 1) & 3)) << 3);
}

// XCD-aware block mapping: blocks sharing an A-panel (all nBn bn's of one bm)
// get linear ids differing by 8 -> same XCD (id%8), temporally adjacent.
template <int CB>
__device__ __forceinline__ void xcd_map(int x, int nBm, int& bm, int& bn) {
    if ((nBm & 7) == 0) {
        int j = x & 7, s = x >> 3;
        bn = s & ((1 << CB) - 1);
        bm = ((s >> CB) << 3) | j;
    } else {
        bm = x >> CB;
        bn = x & ((1 << CB) - 1);
    }
}

// ---------------------------------------------------------------------------
// BatchNorm statistics + fused f32->bf16 states conversion.
// ---------------------------------------------------------------------------
__global__ __launch_bounds__(256) void bnPart(const float* __restrict__ states,
                                              float* __restrict__ part,
                                              bf16* __restrict__ sbf) {
    int blk = blockIdx.x;
    int e = blk >> 6, sl = blk & 63;
    int tid = threadIdx.x, n = tid & 63, rg = tid >> 6;
    const long rowBase = (long)e * B_ + (long)sl * 256;
    const float* base = states + rowBase * 64;
    float s1 = 0.f, s2 = 0.f;
    for (int i = 0; i < 64; ++i) {
        float v = base[(rg + i * 4) * 64 + n];
        s1 += v; s2 += v * v;
        sbf[(rowBase + rg + i * 4) * 64 + n] = f2bf(v);
    }
    __shared__ float sh[2][4][64];
    sh[0][rg][n] = s1; sh[1][rg][n] = s2;
    __syncthreads();
    if (tid < 64) {
        float t1 = sh[0][0][n] + sh[0][1][n] + sh[0][2][n] + sh[0][3][n];
        float t2 = sh[1][0][n] + sh[1][1][n] + sh[1][2][n] + sh[1][3][n];
        part[((long)blk * 64 + n) * 2 + 0] = t1;
        part[((long)blk * 64 + n) * 2 + 1] = t2;
    }
}

__global__ void bnFin(const float* __restrict__ part, float* __restrict__ mu_rstd) {
    int idx = blockIdx.x * blockDim.x + threadIdx.x;  // e*64+n
    if (idx >= E_ * 64) return;
    int e = idx >> 6, n = idx & 63;
    float s1 = 0.f, s2 = 0.f;
    for (int sl = 0; sl < 64; ++sl) {
        s1 += part[(((long)e * 64 + sl) * 64 + n) * 2 + 0];
        s2 += part[(((long)e * 64 + sl) * 64 + n) * 2 + 1];
    }
    float mu = s1 / (float)B_;
    float var = s2 / (float)B_ - mu * mu;
    mu_rstd[idx * 2 + 0] = mu;
    mu_rstd[idx * 2 + 1] = rsqrtf(var + 1e-5f);
}

// Fold BN into encoder weight
__global__ void foldEnc(const float* __restrict__ W_enc, const float* __restrict__ b_enc,
                        const float* __restrict__ mu_rstd,
                        bf16* __restrict__ WencfT, float* __restrict__ bencf) {
    int idx = blockIdx.x * 256 + threadIdx.x;  // E*H = 4096
    int e = idx >> 9, h = idx & 511;
    float acc = b_enc[e * 512 + h];
    for (int n = 0; n < 64; ++n) {
        float mu = mu_rstd[(e * 64 + n) * 2 + 0];
        float rs = mu_rstd[(e * 64 + n) * 2 + 1];
        float w = W_enc[((long)e * 64 + n) * 512 + h];
        WencfT[((long)e * 512 + h) * 64 + n] = f2bf(w * rs);
        acc -= mu * rs * w;
    }
    bencf[e * 512 + h] = acc;
}

// ---------------------------------------------------------------------------
// All weight packing + pre_actions f32->bf16, fused into one dispatch.
// ---------------------------------------------------------------------------
__global__ __launch_bounds__(256) void packAll(
    const float* __restrict__ W_pre, const float* __restrict__ W_actor,
    const float* __restrict__ Wsel, const float* __restrict__ Wk,
    const float* __restrict__ Wv, const float* __restrict__ wm,
    const float* __restrict__ wl, const float* __restrict__ pre_actions,
    bf16* __restrict__ WpreT, bf16* __restrict__ WactorT, bf16* __restrict__ WselT,
    bf16* __restrict__ WkvaT, bf16* __restrict__ WmlT, bf16* __restrict__ pa_bf) {
    int bx = blockIdx.x, tid = threadIdx.x;
    if (bx < 2048) {  // WpreT / WactorT: out[n*512+k] = in[k*512+n]
        const float* in = (bx < 1024) ? W_pre : W_actor;
        bf16* out = (bx < 1024) ? WpreT : WactorT;
        int idx = (bx & 1023) * 256 + tid;
        int n = idx >> 9, k = idx & 511;
        out[idx] = f2bf(in[k * 512 + n]);
    } else if (bx < 3072) {  // WselT: [(a*64+dd)*512+h] = Wsel[a][h][dd]
        int idx = (bx - 2048) * 256 + tid;
        int n = idx >> 9, h = idx & 511;
        int a = n >> 6, dd = n & 63;
        WselT[idx] = f2bf(Wsel[((long)a * 512 + h) * 64 + dd]);
    } else if (bx < 5120) {  // WkvaT: row a*128+j -> (j<64?Wk:Wv)[a][:,j&63]
        int idx = (bx - 3072) * 256 + tid;
        int n = idx >> 9, h = idx & 511;
        int a = n >> 7, j = n & 127;
        const float* src = (j < 64) ? Wk : Wv;
        WkvaT[idx] = f2bf(src[((long)a * 512 + h) * 64 + (j & 63)]);
    } else if (bx < 5376) {  // WmlT [128][512]
        int idx = (bx - 5120) * 256 + tid;
        int n = idx >> 9, k = idx & 511;
        float v = (n < 64) ? wm[k * 64 + n] : wl[k * 64 + (n - 64)];
        WmlT[idx] = f2bf(v);
    } else {  // pa_bf: float4 cvt, 8192 blocks cover B*512/4 exactly
        int i = (bx - 5376) * 256 + tid;
        float4 v = ((const float4*)pre_actions)[i];
        bf16 o[4] = {f2bf(v.x), f2bf(v.y), f2bf(v.z), f2bf(v.w)};
        __builtin_memcpy(pa_bf + (long)i * 4, o, 8);
    }
}

// ---------------------------------------------------------------------------
// Generic MFMA GEMM, XOR-swizzled LDS, XCD-aware block mapping.
// C[M][Nn] = act(A[M][K] * BT[Nn][K]^T + bias)
// OUTF: 0 bf16 out; 1 f32 out; 2 final mean/logstd split; 4 encs [b][e][512]
// ---------------------------------------------------------------------------
template <int ACT, int OUTF, bool HAS_BIAS, int CB>
__global__ __launch_bounds__(256) void gemm_bt(
    const bf16* __restrict__ Ag, const bf16* __restrict__ Bg,
    const float* __restrict__ bias, const float* __restrict__ bias2,
    void* __restrict__ out, void* __restrict__ out2,
    int M, int Nn, int K, long sA, long sB, long sBias, long sO) {
    const int tid = threadIdx.x, lane = tid & 63, wid = tid >> 6;
    const int wm = wid >> 1, wn = wid & 1;
    int bm, bn;
    xcd_map<CB>(blockIdx.x, gridDim.x >> CB, bm, bn);
    const int bz = blockIdx.z;
    const bf16* Aptr = Ag + (long)bz * sA + (long)bm * 128 * K;
    const bf16* Bptr = Bg + (long)bz * sB + (long)bn * 128 * K;

    __shared__ __align__(16) short sAl[128 * 64];
    __shared__ __align__(16) short sBl[128 * 64];

    const int srow = lane >> 3;
    const int scol = (((lane & 7) ^ srow) << 3);

    f4v acc[4][4];
#pragma unroll
    for (int i = 0; i < 4; ++i)
#pragma unroll
        for (int j = 0; j < 4; ++j) acc[i][j] = f4v{0.f, 0.f, 0.f, 0.f};

    for (int k0 = 0; k0 < K; k0 += 64) {
#pragma unroll
        for (int i = 0; i < 4; ++i) {
            int r = (wid * 4 + i) * 8 + srow;
            async_load16(Aptr + (long)r * K + k0 + scol, (char*)sAl + (wid * 4 + i) * 1024);
            async_load16(Bptr + (long)r * K + k0 + scol, (char*)sBl + (wid * 4 + i) * 1024);
        }
        __syncthreads();
#pragma unroll
        for (int kk = 0; kk < 64; kk += 32) {
            int krow = kk + (lane >> 4) * 8;
            s8v af[4], bfr[4];
#pragma unroll
            for (int mi = 0; mi < 4; ++mi)
                af[mi] = *(const s8v*)(sAl + swz_off(wm * 64 + mi * 16 + (lane & 15), krow));
#pragma unroll
            for (int ni = 0; ni < 4; ++ni)
                bfr[ni] = *(const s8v*)(sBl + swz_off(wn * 64 + ni * 16 + (lane & 15), krow));
#pragma unroll
            for (int mi = 0; mi < 4; ++mi)
#pragma unroll
                for (int ni = 0; ni < 4; ++ni)
                    acc[mi][ni] = __builtin_amdgcn_mfma_f32_16x16x32_bf16(
                        af[mi], bfr[ni], acc[mi][ni], 0, 0, 0);
        }
        __syncthreads();
    }

    long m0 = (long)bm * 128 + wm * 64;
    long n0 = (long)bn * 128 + wn * 64;
#pragma unroll
    for (int mi = 0; mi < 4; ++mi)
#pragma unroll
        for (int ni = 0; ni < 4; ++ni)
#pragma unroll
            for (int r = 0; r < 4; ++r) {
                long gm = m0 + mi * 16 + (lane >> 4) * 4 + r;
                long gn = n0 + ni * 16 + (lane & 15);
                float v = acc[mi][ni][r];
                if constexpr (HAS_BIAS) v += bias[sBias * bz + gn];
                if constexpr (ACT == 1) v = (v >= 0.f) ? v : 0.01f * v;
                if constexpr (ACT == 2) v = fmaxf(v, 0.f);
                if constexpr (OUTF == 0) {
                    ((bf16*)out)[(long)bz * sO + gm * Nn + gn] = f2bf(v);
                } else if constexpr (OUTF == 1) {
                    ((float*)out)[(long)bz * sO + gm * Nn + gn] = v;
                } else if constexpr (OUTF == 2) {
                    if (gn < 64) {
                        ((float*)out)[gm * 64 + gn] = v + bias[gn];
                    } else {
                        float w = v + bias2[gn - 64];
                        w = fminf(fmaxf(w, -20.f), 2.f);
                        ((float*)out2)[gm * 64 + (gn - 64)] = w;
                    }
                } else {  // OUTF == 4: encs reordered [b][E][512], bz = e
                    ((bf16*)out)[(gm * E_ + bz) * 512 + gn] = f2bf(v);
                }
            }
}

// ---------------------------------------------------------------------------
// Fused keys/vals GEMM + softmax-attention (XCD-swizzled).
// A = encs [Bc*E][512] bf16 (row = b*8+e). B = WkvaT [1024][512].
// Block (bm, a): 128 rows (16 b x 8 e) x 128 cols (keys|vals of head a).
//
// This round: BK=32 -- combines R7's 64x64 wave tiles (acc[4][4], 32 FLOP
// per LDS byte, 4.19M ds_read_b128) with R6's occupancy (4 waves/SIMD):
// staging LDS drops to 32 KB (A dbuf 16K + B dbuf 16K), high-water mark is
// the 34.8 KB epilogue overlay -> 4 blocks/CU x 4 waves = 16 waves/CU.
// 16 K-steps, one barrier each, issue-early staging (R6-proven).
// New [128][32] swizzle: slot (row,gs) holds k-group gs^((row>>1)&3);
// fragment reads alias 2-way (free).  Arithmetic bit-identical.
// ---------------------------------------------------------------------------
__global__ __launch_bounds__(256, 4) void kv_attn(
    const bf16* __restrict__ Ag, const bf16* __restrict__ Bg,
    const float* __restrict__ bv, const float* __restrict__ sel,
    float* __restrict__ actor_f32, bf16* __restrict__ attn_bf, int b0) {
    const int tid = threadIdx.x, lane = tid & 63, wid = tid >> 6;
    const int wm = wid >> 1, wn = wid & 1;  // wave tile: rows wm*64, cols wn*64
    int bm, a;
    xcd_map<3>(blockIdx.x, gridDim.x >> 3, bm, a);
    const bf16* Aptr = Ag + (long)bm * 128 * 512;
    const bf16* Bptr = Bg + (long)a * 128 * 512;

    // shorts: [0,4096) A buf0   [4096,8192) A buf1   [8192,12288) B buf0
    // [12288,16384) B buf1.  Epilogue overlay: keysC [128][72] at 0,
    // vT [64][128] at 9216.  High-water = 17408 shorts = 34.8 KB.
    __shared__ __align__(16) short smem[17408];
    __shared__ float lgs[128];  // per-row logits (diag)

    const long bgBase = (long)b0 + (long)bm * 16;

    // Staging: each tile is 128 rows x 32 shorts = 8 KB = 512 chunks of 16 B;
    // 256 threads stage 2 chunks each per matrix.  Chunk c -> LDS offset
    // c*16B (linear, as global_load_lds requires); row = c>>2, slot gs = c&3;
    // the global source k-group is gs ^ ((row>>1)&3)  (inverse == forward).
    auto stage = [&](int kt, int buf) {
#pragma unroll
        for (int i = 0; i < 2; ++i) {
            int c = tid + i * 256;
            int r = c >> 2;
            int g = (c & 3) ^ ((r >> 1) & 3);
            async_load16(Aptr + (long)r * 512 + kt * 32 + g * 8,
                         (char*)smem + buf * 8192 + c * 16);
            async_load16(Bptr + (long)r * 512 + kt * 32 + g * 8,
                         (char*)smem + 16384 + buf * 8192 + c * 16);
        }
    };

    f4v acc[4][4];
#pragma unroll
    for (int i = 0; i < 4; ++i)
#pragma unroll
        for (int j = 0; j < 4; ++j) acc[i][j] = f4v{0.f, 0.f, 0.f, 0.f};

    stage(0, 0);
    __syncthreads();
    int cur = 0;
    for (int t = 0; t < 16; ++t) {
        if (t < 15) stage(t + 1, cur ^ 1);  // issue-early: drain covered by compute
        const short* sAc = smem + cur * 4096;
        const short* sBc = smem + 8192 + cur * 4096;
        const int g = lane >> 4;  // k-group; krow = g*8
        s8v af[4], bfr[4];
#pragma unroll
        for (int mi = 0; mi < 4; ++mi)
            af[mi] = *(const s8v*)(sAc + swz32(wm * 64 + mi * 16 + (lane & 15), g));
#pragma unroll
        for (int ni = 0; ni < 4; ++ni)
            bfr[ni] = *(const s8v*)(sBc + swz32(wn * 64 + ni * 16 + (lane & 15), g));
#pragma unroll
        for (int mi = 0; mi < 4; ++mi)
#pragma unroll
            for (int ni = 0; ni < 4; ++ni)
                acc[mi][ni] = __builtin_amdgcn_mfma_f32_16x16x32_bf16(
                    af[mi], bfr[ni], acc[mi][ni], 0, 0, 0);
        __syncthreads();  // one barrier/step: staged buffer ready, reads done
        cur ^= 1;
    }

    // ---- epilogue: keys -> keysC [128][72]; vals -> transposed swizzled vT ----
    short* keysC = smem;         // 128*72 = 9216 shorts
    short* vT    = smem + 9216;  // 64*128 shorts; vT[d*128 + (row ^ ((d&15)<<3))]
    const int quad = lane >> 4, cl = lane & 15;
#pragma unroll
    for (int mi = 0; mi < 4; ++mi)
#pragma unroll
        for (int ni = 0; ni < 4; ++ni)
#pragma unroll
            for (int r = 0; r < 4; ++r) {
                int row = wm * 64 + mi * 16 + quad * 4 + r;
                float v = acc[mi][ni][r];
                if (wn == 0) {  // keys half
                    keysC[row * 72 + ni * 16 + cl] = f2bfs(v);
                } else {        // vals half: bias + leaky, transposed store
                    int d = ni * 16 + cl;
                    v += bv[a * 64 + d];
                    v = (v >= 0.f) ? v : 0.01f * v;
                    vT[d * 128 + (row ^ ((d & 15) << 3))] = f2bfs(v);
                }
            }

    // sel B-fragments for the logits MFMA (loaded post-GEMM): lane holds
    // B[k = kk*32 + quad*8 + j][n = cl] = sel[bgBase + cl][a*64 + k] * 0.125.
    // hi+lo split keeps f32-grade precision through the bf16 MFMA.
    s8v bselH[2], bselL[2];
#pragma unroll
    for (int kk = 0; kk < 2; ++kk) {
        const float* sp = sel + (bgBase + cl) * 512 + a * 64 + kk * 32 + quad * 8;
#pragma unroll
        for (int j = 0; j < 8; ++j) {
            float s = sp[j] * 0.125f;
            short h = f2bfs(s);
            bselH[kk][j] = h;
            bselL[kk][j] = f2bfs(s - bfs2f(h));
        }
    }
    __syncthreads();

    // ---- logits via MFMA: wave wid handles rows [wid*32, wid*32+32) ----
    {
        f4v lgacc[2] = {f4v{0.f, 0.f, 0.f, 0.f}, f4v{0.f, 0.f, 0.f, 0.f}};
#pragma unroll
        for (int kk = 0; kk < 2; ++kk) {
#pragma unroll
            for (int mi = 0; mi < 2; ++mi) {
                s8v af = *(const s8v*)(keysC + (wid * 32 + mi * 16 + cl) * 72 +
                                       kk * 32 + quad * 8);
                lgacc[mi] = __builtin_amdgcn_mfma_f32_16x16x32_bf16(
                    af, bselH[kk], lgacc[mi], 0, 0, 0);
                lgacc[mi] = __builtin_amdgcn_mfma_f32_16x16x32_bf16(
                    af, bselL[kk], lgacc[mi], 0, 0, 0);
            }
        }
        // Extract diagonal: D col (lane&15) must equal b_local (= row>>3).
#pragma unroll
        for (int mi = 0; mi < 2; ++mi)
#pragma unroll
            for (int r = 0; r < 4; ++r) {
                int grow = wid * 32 + mi * 16 + quad * 4 + r;
                if (cl == (grow >> 3)) lgs[grow] = lgacc[mi][r];
            }
    }
    __syncthreads();

    // ---- attention: each wave handles 4 b's; lane = d ----
#pragma unroll
    for (int t = 0; t < 4; ++t) {
        int lb = wid * 4 + t, row0 = lb * 8;
        s8v vvv = *(const s8v*)(vT + lane * 128 + (row0 ^ ((lane & 15) << 3)));
        float lg[8], vv[8];
#pragma unroll
        for (int e = 0; e < 8; ++e) {
            vv[e] = bfs2f(vvv[e]);
            lg[e] = lgs[row0 + e];  // broadcast read
        }
        float mx = lg[0];
#pragma unroll
        for (int e = 1; e < 8; ++e) mx = fmaxf(mx, lg[e]);
        float ssum = 0.f, w[8];
#pragma unroll
        for (int e = 0; e < 8; ++e) { w[e] = __expf(lg[e] - mx); ssum += w[e]; }
        float inv = 1.f / ssum;
        float at = 0.f;
#pragma unroll
        for (int e = 0; e < 8; ++e) at += vv[e] * (w[e] * inv);
        long o = (bgBase + lb) * 512 + a * 64 + lane;
        actor_f32[o] = at;
        attn_bf[o] = f2bf(at);
    }
}

// ---------------------------------------------------------------------------
extern "C" void kernel_launch(void* const* d_in, const int* in_sizes, int n_in,
                              void* d_out, int out_size, void* d_ws, size_t ws_size,
                              hipStream_t stream) {
    (void)in_sizes; (void)n_in; (void)out_size;
    const float* states      = (const float*)d_in[0];
    const float* pre_actions = (const float*)d_in[1];
    const float* W_enc       = (const float*)d_in[2];
    const float* b_enc       = (const float*)d_in[3];
    const float* W_pre       = (const float*)d_in[4];
    const float* b_pre       = (const float*)d_in[5];
    const float* Wk          = (const float*)d_in[6];
    const float* Wsel        = (const float*)d_in[7];
    const float* Wv          = (const float*)d_in[8];
    const float* bv          = (const float*)d_in[9];
    const float* W_actor     = (const float*)d_in[10];
    const float* b_actor     = (const float*)d_in[11];
    const float* W_mean      = (const float*)d_in[12];
    const float* b_mean      = (const float*)d_in[13];
    const float* W_logstd    = (const float*)d_in[14];
    const float* b_logstd    = (const float*)d_in[15];

    char* ws = (char*)d_ws;
    size_t off = 0;
    auto alloc = [&](size_t bytes) -> void* {
        void* p = ws + off;
        off = (off + bytes + 255) & ~(size_t)255;
        return p;
    };
    float* mu_rstd = (float*)alloc((size_t)E_ * 64 * 2 * 4);
    float* bnpart  = (float*)alloc((size_t)E_ * 64 * 64 * 2 * 4);
    bf16* WencfT   = (bf16*)alloc((size_t)E_ * 512 * 64 * 2);
    float* bencf   = (float*)alloc((size_t)E_ * 512 * 4);
    bf16* WpreT    = (bf16*)alloc((size_t)512 * 512 * 2);
    bf16* WselT    = (bf16*)alloc((size_t)512 * 512 * 2);
    bf16* WkvaT    = (bf16*)alloc((size_t)1024 * 512 * 2);
    bf16* WactorT  = (bf16*)alloc((size_t)512 * 512 * 2);
    bf16* WmlT     = (bf16*)alloc((size_t)128 * 512 * 2);
    bf16* pa_bf    = (bf16*)alloc((size_t)B_ * 512 * 2);   // aliased later as p_attn
    bf16* p_pre    = (bf16*)alloc((size_t)B_ * 512 * 2);   // aliased later as p_x
    float* p_sel   = (float*)alloc((size_t)B_ * 512 * 4);
    bf16* s_bf     = (bf16*)alloc((size_t)E_ * B_ * 64 * 2);  // bf16 states (full B)
    bf16* p_attn = pa_bf;   // pre_actions bf16 dead after pre GEMM
    bf16* p_x    = p_pre;   // pre dead after sel GEMM

    // chunk over B: per-chunk bytes = Bc*(E*512*2) = Bc*8192 (encs only)
    size_t remaining = (ws_size > off) ? ws_size - off : 0;
    int Bc = B_;
    while (Bc > 128 && (size_t)Bc * 8192 + 4096 > remaining) Bc >>= 1;
    const int NC = B_ / Bc;
    bf16* c_encs = (bf16*)alloc((size_t)E_ * Bc * 512 * 2);  // [b][e][512]

    // --- prep (one fused dispatch + BN chain; bnPart also emits s_bf) ---
    packAll<<<13568, 256, 0, stream>>>(W_pre, W_actor, Wsel, Wk, Wv, W_mean, W_logstd,
                                       pre_actions, WpreT, WactorT, WselT, WkvaT, WmlT,
                                       pa_bf);
    bnPart<<<512, 256, 0, stream>>>(states, bnpart, s_bf);
    bnFin<<<2, 256, 0, stream>>>(bnpart, mu_rstd);
    foldEnc<<<16, 256, 0, stream>>>(W_enc, b_enc, mu_rstd, WencfT, bencf);

    // --- pre / sel (full B) ---
    gemm_bt<1, 0, true, 2><<<dim3((B_ / 128) << 2, 1, 1), 256, 0, stream>>>(
        pa_bf, WpreT, b_pre, nullptr, p_pre, nullptr, B_, 512, 512, 0, 0, 0, 0);
    gemm_bt<0, 1, false, 2><<<dim3((B_ / 128) << 2, 1, 1), 256, 0, stream>>>(
        p_pre, WselT, nullptr, nullptr, p_sel, nullptr, B_, 512, 512, 0, 0, 0, 0);

    // --- chunked: encoder GEMM ([b][e][512]), fused kv+attn ---
    float* actor_out = (float*)d_out + 2L * B_ * 64;
    for (int c = 0; c < NC; ++c) {
        int b0 = c * Bc;
        gemm_bt<1, 4, true, 2><<<dim3((Bc / 128) << 2, 1, E_), 256, 0, stream>>>(
            s_bf + (long)b0 * 64, WencfT, bencf, nullptr, c_encs, nullptr, Bc, 512, 64,
            (long)B_ * 64, (long)512 * 64, 512, 0);
        kv_attn<<<dim3((Bc / 16) * 8, 1, 1), 256, 0, stream>>>(
            c_encs, WkvaT, bv, p_sel, actor_out, p_attn, b0);
    }

    // --- actor + heads ---
    gemm_bt<2, 0, true, 2><<<dim3((B_ / 128) << 2, 1, 1), 256, 0, stream>>>(
        p_attn, WactorT, b_actor, nullptr, p_x, nullptr, B_, 512, 512, 0, 0, 0, 0);
    gemm_bt<0, 2, false, 0><<<dim3(B_ / 128, 1, 1), 256, 0, stream>>>(
        p_x, WmlT, b_mean, b_logstd, (float*)d_out, (float*)d_out + (long)B_ * 64,
        B_, 128, 512, 0, 0, 0, 0);
}

// Round 9
// 460.898 us; speedup vs baseline: 1.1920x; 1.0475x over previous
//
#include <hip/hip_runtime.h>
#include <hip/hip_bf16.h>
#include <stdint.h>

#define E_ 8
#define B_ 16384
#define N_ 64
#define H_ 512
#define A_ 8
#define D_ 64

typedef __hip_bfloat16 bf16;
typedef __attribute__((ext_vector_type(8))) short s8v;     // 8 x bf16 (4 VGPRs)
typedef __attribute__((ext_vector_type(4))) float f4v;     // MFMA accum

__device__ __forceinline__ float bf2f(bf16 v) { return __bfloat162float(v); }
__device__ __forceinline__ bf16 f2bf(float v) { return __float2bfloat16(v); }
__device__ __forceinline__ short f2bfs(float v) {
    bf16 b = f2bf(v); short s; __builtin_memcpy(&s, &b, 2); return s;
}
__device__ __forceinline__ float bfs2f(short s) {
    bf16 b; __builtin_memcpy(&b, &s, 2); return bf2f(b);
}

__device__ __forceinline__ void async_load16(const void* g, void* l) {
    __builtin_amdgcn_global_load_lds(
        (const __attribute__((address_space(1))) void*)g,
        (__attribute__((address_space(3))) void*)l, 16, 0, 0);
}

// Swizzled LDS short-offset for a row-major [R][32]-short tile (BK=32):
// slot (row, gs) holds global K-group gs ^ ((row>>1)&3).  To READ global
// group g of row r, use offset swz32(r, g).  Fragment reads alias 2-way
// across banks (free, m136).
__device__ __forceinline__ int swz32(int row, int g) {
    return row * 32 + ((g ^ ((row >> 1) & 3)) << 3);
}

// XCD-aware block mapping: blocks sharing an A-panel (all nBn bn's of one bm)
// get linear ids differing by 8 -> same XCD (id%8), temporally adjacent.
template <int CB>
__device__ __forceinline__ void xcd_map(int x, int nBm, int& bm, int& bn) {
    if ((nBm & 7) == 0) {
        int j = x & 7, s = x >> 3;
        bn = s & ((1 << CB) - 1);
        bm = ((s >> CB) << 3) | j;
    } else {
        bm = x >> CB;
        bn = x & ((1 << CB) - 1);
    }
}

// ---------------------------------------------------------------------------
// BatchNorm statistics + fused f32->bf16 states conversion.
// ---------------------------------------------------------------------------
__global__ __launch_bounds__(256) void bnPart(const float* __restrict__ states,
                                              float* __restrict__ part,
                                              bf16* __restrict__ sbf) {
    int blk = blockIdx.x;
    int e = blk >> 6, sl = blk & 63;
    int tid = threadIdx.x, n = tid & 63, rg = tid >> 6;
    const long rowBase = (long)e * B_ + (long)sl * 256;
    const float* base = states + rowBase * 64;
    float s1 = 0.f, s2 = 0.f;
    for (int i = 0; i < 64; ++i) {
        float v = base[(rg + i * 4) * 64 + n];
        s1 += v; s2 += v * v;
        sbf[(rowBase + rg + i * 4) * 64 + n] = f2bf(v);
    }
    __shared__ float sh[2][4][64];
    sh[0][rg][n] = s1; sh[1][rg][n] = s2;
    __syncthreads();
    if (tid < 64) {
        float t1 = sh[0][0][n] + sh[0][1][n] + sh[0][2][n] + sh[0][3][n];
        float t2 = sh[1][0][n] + sh[1][1][n] + sh[1][2][n] + sh[1][3][n];
        part[((long)blk * 64 + n) * 2 + 0] = t1;
        part[((long)blk * 64 + n) * 2 + 1] = t2;
    }
}

__global__ void bnFin(const float* __restrict__ part, float* __restrict__ mu_rstd) {
    int idx = blockIdx.x * blockDim.x + threadIdx.x;  // e*64+n
    if (idx >= E_ * 64) return;
    int e = idx >> 6, n = idx & 63;
    float s1 = 0.f, s2 = 0.f;
    for (int sl = 0; sl < 64; ++sl) {
        s1 += part[(((long)e * 64 + sl) * 64 + n) * 2 + 0];
        s2 += part[(((long)e * 64 + sl) * 64 + n) * 2 + 1];
    }
    float mu = s1 / (float)B_;
    float var = s2 / (float)B_ - mu * mu;
    mu_rstd[idx * 2 + 0] = mu;
    mu_rstd[idx * 2 + 1] = rsqrtf(var + 1e-5f);
}

// Fold BN into encoder weight
__global__ void foldEnc(const float* __restrict__ W_enc, const float* __restrict__ b_enc,
                        const float* __restrict__ mu_rstd,
                        bf16* __restrict__ WencfT, float* __restrict__ bencf) {
    int idx = blockIdx.x * 256 + threadIdx.x;  // E*H = 4096
    int e = idx >> 9, h = idx & 511;
    float acc = b_enc[e * 512 + h];
    for (int n = 0; n < 64; ++n) {
        float mu = mu_rstd[(e * 64 + n) * 2 + 0];
        float rs = mu_rstd[(e * 64 + n) * 2 + 1];
        float w = W_enc[((long)e * 64 + n) * 512 + h];
        WencfT[((long)e * 512 + h) * 64 + n] = f2bf(w * rs);
        acc -= mu * rs * w;
    }
    bencf[e * 512 + h] = acc;
}

// ---------------------------------------------------------------------------
// All weight packing + pre_actions f32->bf16, fused into one dispatch.
// ---------------------------------------------------------------------------
__global__ __launch_bounds__(256) void packAll(
    const float* __restrict__ W_pre, const float* __restrict__ W_actor,
    const float* __restrict__ Wsel, const float* __restrict__ Wk,
    const float* __restrict__ Wv, const float* __restrict__ wm,
    const float* __restrict__ wl, const float* __restrict__ pre_actions,
    bf16* __restrict__ WpreT, bf16* __restrict__ WactorT, bf16* __restrict__ WselT,
    bf16* __restrict__ WkvaT, bf16* __restrict__ WmlT, bf16* __restrict__ pa_bf) {
    int bx = blockIdx.x, tid = threadIdx.x;
    if (bx < 2048) {  // WpreT / WactorT: out[n*512+k] = in[k*512+n]
        const float* in = (bx < 1024) ? W_pre : W_actor;
        bf16* out = (bx < 1024) ? WpreT : WactorT;
        int idx = (bx & 1023) * 256 + tid;
        int n = idx >> 9, k = idx & 511;
        out[idx] = f2bf(in[k * 512 + n]);
    } else if (bx < 3072) {  // WselT: [(a*64+dd)*512+h] = Wsel[a][h][dd]
        int idx = (bx - 2048) * 256 + tid;
        int n = idx >> 9, h = idx & 511;
        int a = n >> 6, dd = n & 63;
        WselT[idx] = f2bf(Wsel[((long)a * 512 + h) * 64 + dd]);
    } else if (bx < 5120) {  // WkvaT: row a*128+j -> (j<64?Wk:Wv)[a][:,j&63]
        int idx = (bx - 3072) * 256 + tid;
        int n = idx >> 9, h = idx & 511;
        int a = n >> 7, j = n & 127;
        const float* src = (j < 64) ? Wk : Wv;
        WkvaT[idx] = f2bf(src[((long)a * 512 + h) * 64 + (j & 63)]);
    } else if (bx < 5376) {  // WmlT [128][512]
        int idx = (bx - 5120) * 256 + tid;
        int n = idx >> 9, k = idx & 511;
        float v = (n < 64) ? wm[k * 64 + n] : wl[k * 64 + (n - 64)];
        WmlT[idx] = f2bf(v);
    } else {  // pa_bf: float4 cvt, 8192 blocks cover B*512/4 exactly
        int i = (bx - 5376) * 256 + tid;
        float4 v = ((const float4*)pre_actions)[i];
        bf16 o[4] = {f2bf(v.x), f2bf(v.y), f2bf(v.z), f2bf(v.w)};
        __builtin_memcpy(pa_bf + (long)i * 4, o, 8);
    }
}

// ---------------------------------------------------------------------------
// Generic MFMA GEMM, R8-pipeline: BM=64, BN=128, BK=32, 4 waves (32x64 each,
// acc[2][4] = 32 AGPR), A+B double-buffered, issue-early staging, ONE barrier
// per K-step, swz32 LDS (24 KB -> 4 blocks/CU where grid allows).
// C[M][Nn] = act(A[M][K] * BT[Nn][K]^T + bias)
// OUTF: 0 bf16 out; 1 f32 out; 2 final mean/logstd split; 4 encs [b][e][512]
// MFMA K-slice order ascending (bit-identical to the old BK=64 template).
// ---------------------------------------------------------------------------
template <int ACT, int OUTF, bool HAS_BIAS, int CB>
__global__ __launch_bounds__(256, 4) void gemm_bt2(
    const bf16* __restrict__ Ag, const bf16* __restrict__ Bg,
    const float* __restrict__ bias, const float* __restrict__ bias2,
    void* __restrict__ out, void* __restrict__ out2,
    int M, int Nn, int K, long sA, long sB, long sBias, long sO) {
    const int tid = threadIdx.x, lane = tid & 63, wid = tid >> 6;
    const int wm = wid >> 1, wn = wid & 1;  // wave tile: rows wm*32, cols wn*64
    int bm, bn;
    xcd_map<CB>(blockIdx.x, gridDim.x >> CB, bm, bn);
    const int bz = blockIdx.z;
    const bf16* Aptr = Ag + (long)bz * sA + (long)bm * 64 * K;
    const bf16* Bptr = Bg + (long)bz * sB + (long)bn * 128 * K;

    // shorts: [0,2048) A buf0  [2048,4096) A buf1  [4096,8192) B buf0
    // [8192,12288) B buf1.  24.5 KB total.
    __shared__ __align__(16) short smem[12288];

    // Staging: A tile 64x32 shorts = 256 chunks of 16B (1/thread);
    // B tile 128x32 = 512 chunks (2/thread).  Linear LDS dest, pre-swizzled
    // global source (chunk c: row c>>2, slot gs=c&3, src group gs^((r>>1)&3)).
    auto stage = [&](int kt, int buf) {
        {
            int c = tid, r = c >> 2;
            int g = (c & 3) ^ ((r >> 1) & 3);
            async_load16(Aptr + (long)r * K + kt * 32 + g * 8,
                         (char*)smem + buf * 4096 + c * 16);
        }
#pragma unroll
        for (int i = 0; i < 2; ++i) {
            int c = tid + i * 256, r = c >> 2;
            int g = (c & 3) ^ ((r >> 1) & 3);
            async_load16(Bptr + (long)r * K + kt * 32 + g * 8,
                         (char*)smem + 8192 + buf * 8192 + c * 16);
        }
    };

    f4v acc[2][4];
#pragma unroll
    for (int i = 0; i < 2; ++i)
#pragma unroll
        for (int j = 0; j < 4; ++j) acc[i][j] = f4v{0.f, 0.f, 0.f, 0.f};

    stage(0, 0);
    __syncthreads();
    int cur = 0;
    const int nt = K >> 5;
    for (int t = 0; t < nt; ++t) {
        if (t < nt - 1) stage(t + 1, cur ^ 1);  // issue-early
        const short* sAc = smem + cur * 2048;
        const short* sBc = smem + 4096 + cur * 4096;
        const int g = lane >> 4;
        s8v af[2], bfr[4];
#pragma unroll
        for (int mi = 0; mi < 2; ++mi)
            af[mi] = *(const s8v*)(sAc + swz32(wm * 32 + mi * 16 + (lane & 15), g));
#pragma unroll
        for (int ni = 0; ni < 4; ++ni)
            bfr[ni] = *(const s8v*)(sBc + swz32(wn * 64 + ni * 16 + (lane & 15), g));
#pragma unroll
        for (int mi = 0; mi < 2; ++mi)
#pragma unroll
            for (int ni = 0; ni < 4; ++ni)
                acc[mi][ni] = __builtin_amdgcn_mfma_f32_16x16x32_bf16(
                    af[mi], bfr[ni], acc[mi][ni], 0, 0, 0);
        __syncthreads();  // staged buffer ready + reads done
        cur ^= 1;
    }

    long m0 = (long)bm * 64 + wm * 32;
    long n0 = (long)bn * 128 + wn * 64;
    const int quad = lane >> 4, cl = lane & 15;
#pragma unroll
    for (int mi = 0; mi < 2; ++mi)
#pragma unroll
        for (int ni = 0; ni < 4; ++ni)
#pragma unroll
            for (int r = 0; r < 4; ++r) {
                long gm = m0 + mi * 16 + quad * 4 + r;
                long gn = n0 + ni * 16 + cl;
                float v = acc[mi][ni][r];
                if constexpr (HAS_BIAS) v += bias[sBias * bz + gn];
                if constexpr (ACT == 1) v = (v >= 0.f) ? v : 0.01f * v;
                if constexpr (ACT == 2) v = fmaxf(v, 0.f);
                if constexpr (OUTF == 0) {
                    ((bf16*)out)[(long)bz * sO + gm * Nn + gn] = f2bf(v);
                } else if constexpr (OUTF == 1) {
                    ((float*)out)[(long)bz * sO + gm * Nn + gn] = v;
                } else if constexpr (OUTF == 2) {
                    if (gn < 64) {
                        ((float*)out)[gm * 64 + gn] = v + bias[gn];
                    } else {
                        float w = v + bias2[gn - 64];
                        w = fminf(fmaxf(w, -20.f), 2.f);
                        ((float*)out2)[gm * 64 + (gn - 64)] = w;
                    }
                } else {  // OUTF == 4: encs reordered [b][E][512], bz = e
                    ((bf16*)out)[(gm * E_ + bz) * 512 + gn] = f2bf(v);
                }
            }
}

// ---------------------------------------------------------------------------
// Fused keys/vals GEMM + softmax-attention (R8 champion, unchanged).
// ---------------------------------------------------------------------------
__global__ __launch_bounds__(256, 4) void kv_attn(
    const bf16* __restrict__ Ag, const bf16* __restrict__ Bg,
    const float* __restrict__ bv, const float* __restrict__ sel,
    float* __restrict__ actor_f32, bf16* __restrict__ attn_bf, int b0) {
    const int tid = threadIdx.x, lane = tid & 63, wid = tid >> 6;
    const int wm = wid >> 1, wn = wid & 1;  // wave tile: rows wm*64, cols wn*64
    int bm, a;
    xcd_map<3>(blockIdx.x, gridDim.x >> 3, bm, a);
    const bf16* Aptr = Ag + (long)bm * 128 * 512;
    const bf16* Bptr = Bg + (long)a * 128 * 512;

    // shorts: [0,4096) A buf0   [4096,8192) A buf1   [8192,12288) B buf0
    // [12288,16384) B buf1.  Epilogue overlay: keysC [128][72] at 0,
    // vT [64][128] at 9216.  High-water = 17408 shorts = 34.8 KB.
    __shared__ __align__(16) short smem[17408];
    __shared__ float lgs[128];  // per-row logits (diag)

    const long bgBase = (long)b0 + (long)bm * 16;

    auto stage = [&](int kt, int buf) {
#pragma unroll
        for (int i = 0; i < 2; ++i) {
            int c = tid + i * 256;
            int r = c >> 2;
            int g = (c & 3) ^ ((r >> 1) & 3);
            async_load16(Aptr + (long)r * 512 + kt * 32 + g * 8,
                         (char*)smem + buf * 8192 + c * 16);
            async_load16(Bptr + (long)r * 512 + kt * 32 + g * 8,
                         (char*)smem + 16384 + buf * 8192 + c * 16);
        }
    };

    f4v acc[4][4];
#pragma unroll
    for (int i = 0; i < 4; ++i)
#pragma unroll
        for (int j = 0; j < 4; ++j) acc[i][j] = f4v{0.f, 0.f, 0.f, 0.f};

    stage(0, 0);
    __syncthreads();
    int cur = 0;
    for (int t = 0; t < 16; ++t) {
        if (t < 15) stage(t + 1, cur ^ 1);  // issue-early: drain covered by compute
        const short* sAc = smem + cur * 4096;
        const short* sBc = smem + 8192 + cur * 4096;
        const int g = lane >> 4;  // k-group; krow = g*8
        s8v af[4], bfr[4];
#pragma unroll
        for (int mi = 0; mi < 4; ++mi)
            af[mi] = *(const s8v*)(sAc + swz32(wm * 64 + mi * 16 + (lane & 15), g));
#pragma unroll
        for (int ni = 0; ni < 4; ++ni)
            bfr[ni] = *(const s8v*)(sBc + swz32(wn * 64 + ni * 16 + (lane & 15), g));
#pragma unroll
        for (int mi = 0; mi < 4; ++mi)
#pragma unroll
            for (int ni = 0; ni < 4; ++ni)
                acc[mi][ni] = __builtin_amdgcn_mfma_f32_16x16x32_bf16(
                    af[mi], bfr[ni], acc[mi][ni], 0, 0, 0);
        __syncthreads();  // one barrier/step: staged buffer ready, reads done
        cur ^= 1;
    }

    // ---- epilogue: keys -> keysC [128][72]; vals -> transposed swizzled vT ----
    short* keysC = smem;         // 128*72 = 9216 shorts
    short* vT    = smem + 9216;  // 64*128 shorts; vT[d*128 + (row ^ ((d&15)<<3))]
    const int quad = lane >> 4, cl = lane & 15;
#pragma unroll
    for (int mi = 0; mi < 4; ++mi)
#pragma unroll
        for (int ni = 0; ni < 4; ++ni)
#pragma unroll
            for (int r = 0; r < 4; ++r) {
                int row = wm * 64 + mi * 16 + quad * 4 + r;
                float v = acc[mi][ni][r];
                if (wn == 0) {  // keys half
                    keysC[row * 72 + ni * 16 + cl] = f2bfs(v);
                } else {        // vals half: bias + leaky, transposed store
                    int d = ni * 16 + cl;
                    v += bv[a * 64 + d];
                    v = (v >= 0.f) ? v : 0.01f * v;
                    vT[d * 128 + (row ^ ((d & 15) << 3))] = f2bfs(v);
                }
            }

    // sel B-fragments for the logits MFMA (loaded post-GEMM): lane holds
    // B[k = kk*32 + quad*8 + j][n = cl] = sel[bgBase + cl][a*64 + k] * 0.125.
    // hi+lo split keeps f32-grade precision through the bf16 MFMA.
    s8v bselH[2], bselL[2];
#pragma unroll
    for (int kk = 0; kk < 2; ++kk) {
        const float* sp = sel + (bgBase + cl) * 512 + a * 64 + kk * 32 + quad * 8;
#pragma unroll
        for (int j = 0; j < 8; ++j) {
            float s = sp[j] * 0.125f;
            short h = f2bfs(s);
            bselH[kk][j] = h;
            bselL[kk][j] = f2bfs(s - bfs2f(h));
        }
    }
    __syncthreads();

    // ---- logits via MFMA: wave wid handles rows [wid*32, wid*32+32) ----
    {
        f4v lgacc[2] = {f4v{0.f, 0.f, 0.f, 0.f}, f4v{0.f, 0.f, 0.f, 0.f}};
#pragma unroll
        for (int kk = 0; kk < 2; ++kk) {
#pragma unroll
            for (int mi = 0; mi < 2; ++mi) {
                s8v af = *(const s8v*)(keysC + (wid * 32 + mi * 16 + cl) * 72 +
                                       kk * 32 + quad * 8);
                lgacc[mi] = __builtin_amdgcn_mfma_f32_16x16x32_bf16(
                    af, bselH[kk], lgacc[mi], 0, 0, 0);
                lgacc[mi] = __builtin_amdgcn_mfma_f32_16x16x32_bf16(
                    af, bselL[kk], lgacc[mi], 0, 0, 0);
            }
        }
        // Extract diagonal: D col (lane&15) must equal b_local (= row>>3).
#pragma unroll
        for (int mi = 0; mi < 2; ++mi)
#pragma unroll
            for (int r = 0; r < 4; ++r) {
                int grow = wid * 32 + mi * 16 + quad * 4 + r;
                if (cl == (grow >> 3)) lgs[grow] = lgacc[mi][r];
            }
    }
    __syncthreads();

    // ---- attention: each wave handles 4 b's; lane = d ----
#pragma unroll
    for (int t = 0; t < 4; ++t) {
        int lb = wid * 4 + t, row0 = lb * 8;
        s8v vvv = *(const s8v*)(vT + lane * 128 + (row0 ^ ((lane & 15) << 3)));
        float lg[8], vv[8];
#pragma unroll
        for (int e = 0; e < 8; ++e) {
            vv[e] = bfs2f(vvv[e]);
            lg[e] = lgs[row0 + e];  // broadcast read
        }
        float mx = lg[0];
#pragma unroll
        for (int e = 1; e < 8; ++e) mx = fmaxf(mx, lg[e]);
        float ssum = 0.f, w[8];
#pragma unroll
        for (int e = 0; e < 8; ++e) { w[e] = __expf(lg[e] - mx); ssum += w[e]; }
        float inv = 1.f / ssum;
        float at = 0.f;
#pragma unroll
        for (int e = 0; e < 8; ++e) at += vv[e] * (w[e] * inv);
        long o = (bgBase + lb) * 512 + a * 64 + lane;
        actor_f32[o] = at;
        attn_bf[o] = f2bf(at);
    }
}

// ---------------------------------------------------------------------------
extern "C" void kernel_launch(void* const* d_in, const int* in_sizes, int n_in,
                              void* d_out, int out_size, void* d_ws, size_t ws_size,
                              hipStream_t stream) {
    (void)in_sizes; (void)n_in; (void)out_size;
    const float* states      = (const float*)d_in[0];
    const float* pre_actions = (const float*)d_in[1];
    const float* W_enc       = (const float*)d_in[2];
    const float* b_enc       = (const float*)d_in[3];
    const float* W_pre       = (const float*)d_in[4];
    const float* b_pre       = (const float*)d_in[5];
    const float* Wk          = (const float*)d_in[6];
    const float* Wsel        = (const float*)d_in[7];
    const float* Wv          = (const float*)d_in[8];
    const float* bv          = (const float*)d_in[9];
    const float* W_actor     = (const float*)d_in[10];
    const float* b_actor     = (const float*)d_in[11];
    const float* W_mean      = (const float*)d_in[12];
    const float* b_mean      = (const float*)d_in[13];
    const float* W_logstd    = (const float*)d_in[14];
    const float* b_logstd    = (const float*)d_in[15];

    char* ws = (char*)d_ws;
    size_t off = 0;
    auto alloc = [&](size_t bytes) -> void* {
        void* p = ws + off;
        off = (off + bytes + 255) & ~(size_t)255;
        return p;
    };
    float* mu_rstd = (float*)alloc((size_t)E_ * 64 * 2 * 4);
    float* bnpart  = (float*)alloc((size_t)E_ * 64 * 64 * 2 * 4);
    bf16* WencfT   = (bf16*)alloc((size_t)E_ * 512 * 64 * 2);
    float* bencf   = (float*)alloc((size_t)E_ * 512 * 4);
    bf16* WpreT    = (bf16*)alloc((size_t)512 * 512 * 2);
    bf16* WselT    = (bf16*)alloc((size_t)512 * 512 * 2);
    bf16* WkvaT    = (bf16*)alloc((size_t)1024 * 512 * 2);
    bf16* WactorT  = (bf16*)alloc((size_t)512 * 512 * 2);
    bf16* WmlT     = (bf16*)alloc((size_t)128 * 512 * 2);
    bf16* pa_bf    = (bf16*)alloc((size_t)B_ * 512 * 2);   // aliased later as p_attn
    bf16* p_pre    = (bf16*)alloc((size_t)B_ * 512 * 2);   // aliased later as p_x
    float* p_sel   = (float*)alloc((size_t)B_ * 512 * 4);
    bf16* s_bf     = (bf16*)alloc((size_t)E_ * B_ * 64 * 2);  // bf16 states (full B)
    bf16* p_attn = pa_bf;   // pre_actions bf16 dead after pre GEMM
    bf16* p_x    = p_pre;   // pre dead after sel GEMM

    // chunk over B: per-chunk bytes = Bc*(E*512*2) = Bc*8192 (encs only)
    size_t remaining = (ws_size > off) ? ws_size - off : 0;
    int Bc = B_;
    while (Bc > 128 && (size_t)Bc * 8192 + 4096 > remaining) Bc >>= 1;
    const int NC = B_ / Bc;
    bf16* c_encs = (bf16*)alloc((size_t)E_ * Bc * 512 * 2);  // [b][e][512]

    // --- prep (one fused dispatch + BN chain; bnPart also emits s_bf) ---
    packAll<<<13568, 256, 0, stream>>>(W_pre, W_actor, Wsel, Wk, Wv, W_mean, W_logstd,
                                       pre_actions, WpreT, WactorT, WselT, WkvaT, WmlT,
                                       pa_bf);
    bnPart<<<512, 256, 0, stream>>>(states, bnpart, s_bf);
    bnFin<<<2, 256, 0, stream>>>(bnpart, mu_rstd);
    foldEnc<<<16, 256, 0, stream>>>(W_enc, b_enc, mu_rstd, WencfT, bencf);

    // --- pre / sel (full B): 1024 blocks = 4/CU, 16 waves/CU ---
    gemm_bt2<1, 0, true, 2><<<dim3((B_ / 64) << 2, 1, 1), 256, 0, stream>>>(
        pa_bf, WpreT, b_pre, nullptr, p_pre, nullptr, B_, 512, 512, 0, 0, 0, 0);
    gemm_bt2<0, 1, false, 2><<<dim3((B_ / 64) << 2, 1, 1), 256, 0, stream>>>(
        p_pre, WselT, nullptr, nullptr, p_sel, nullptr, B_, 512, 512, 0, 0, 0, 0);

    // --- chunked: encoder GEMM ([b][e][512]), fused kv+attn ---
    float* actor_out = (float*)d_out + 2L * B_ * 64;
    for (int c = 0; c < NC; ++c) {
        int b0 = c * Bc;
        gemm_bt2<1, 4, true, 2><<<dim3((Bc / 64) << 2, 1, E_), 256, 0, stream>>>(
            s_bf + (long)b0 * 64, WencfT, bencf, nullptr, c_encs, nullptr, Bc, 512, 64,
            (long)B_ * 64, (long)512 * 64, 512, 0);
        kv_attn<<<dim3((Bc / 16) * 8, 1, 1), 256, 0, stream>>>(
            c_encs, WkvaT, bv, p_sel, actor_out, p_attn, b0);
    }

    // --- actor + heads ---
    gemm_bt2<2, 0, true, 2><<<dim3((B_ / 64) << 2, 1, 1), 256, 0, stream>>>(
        p_attn, WactorT, b_actor, nullptr, p_x, nullptr, B_, 512, 512, 0, 0, 0, 0);
    gemm_bt2<0, 2, false, 0><<<dim3(B_ / 64, 1, 1), 256, 0, stream>>>(
        p_x, WmlT, b_mean, b_logstd, (float*)d_out, (float*)d_out + (long)B_ * 64,
        B_, 128, 512, 0, 0, 0, 0);
}